// Round 22
// baseline (208.958 us; speedup 1.0000x reference)
//
#include <hip/hip_runtime.h>
#include <hip/hip_bf16.h>

// Problem constants
#define TT 128
#define EE 192
#define HH 192
#define SCALE_F 0.07216878364870322f
#define LOG2E_F 1.4426950408889634f

typedef float f32x4 __attribute__((ext_vector_type(4)));
typedef short short8 __attribute__((ext_vector_type(8)));
typedef short short4v __attribute__((ext_vector_type(4)));

// RTNE fp32->bf16 (manual; cold kernels)
__device__ inline unsigned short f2bf(float x) {
  union { float f; unsigned u; } v; v.f = x;
  unsigned r = v.u + 0x7FFFu + ((v.u >> 16) & 1u);
  return (unsigned short)(r >> 16);
}
// hot path: packed RTNE via v_cvt_pk_bf16_f32
__device__ inline unsigned pack2bf(float a, float b) {
  __hip_bfloat162 h = __float22bfloat162_rn(float2{a, b});
  union { __hip_bfloat162 h2; unsigned u; } c; c.h2 = h;
  return c.u;
}

// ---------------------------------------------------------------------------
// pack_wv: Wv[h][e] fp32 -> frag-major bf16 (72 frags x 1KB).
// frag f = tile*6 + es; lane(lg,lr) j=0..7 -> Wv[16*tile+lr][32*es+8*lg+j]
// ---------------------------------------------------------------------------
__global__ void pack_wv(const float* __restrict__ Wv, short* __restrict__ out) {
  int f = blockIdx.x * 4 + (threadIdx.x >> 6);  // 72 frags, grid 18 x 256
  int lane = threadIdx.x & 63, lg = lane >> 4, lr = lane & 15;
  int tile = f / 6, es = f % 6;
  const float* p = Wv + (16 * tile + lr) * EE + 32 * es + 8 * lg;
  float4 a = *(const float4*)p;
  float4 b = *(const float4*)(p + 4);
  short8 h;
  h[0] = (short)f2bf(a.x); h[1] = (short)f2bf(a.y);
  h[2] = (short)f2bf(a.z); h[3] = (short)f2bf(a.w);
  h[4] = (short)f2bf(b.x); h[5] = (short)f2bf(b.y);
  h[6] = (short)f2bf(b.z); h[7] = (short)f2bf(b.w);
  *(short8*)(out + ((size_t)f * 64 + lane) * 8) = h;
}

// ---------------------------------------------------------------------------
// make_mt: MT[e2][e1] = sum_h Wq[h][e1]*Wk[h][e2], fp32 accumulate, stored
// frag-major bf16 (MT plays the "Wq" role in the transpose-proj):
// frag f = tile*6+es; lane(lg,lr) j -> MT[16*tile+lr][32*es+8*lg+j].
// ---------------------------------------------------------------------------
__global__ __launch_bounds__(256)
void make_mt(const float* __restrict__ Wq, const float* __restrict__ Wk,
             short* __restrict__ out) {
  __shared__ float red[4][64][8];
  const int f = blockIdx.x;  // 72
  const int tid = threadIdx.x;
  const int w = tid >> 6, lane = tid & 63, lg = lane >> 4, lr = lane & 15;
  const int tile = f / 6, es = f % 6;
  const int kcol = 16 * tile + lr;      // e2
  const int e1b = 32 * es + 8 * lg;     // e1 base

  float acc[8];
#pragma unroll
  for (int j = 0; j < 8; ++j) acc[j] = 0.f;
#pragma unroll 4
  for (int h = 48 * w; h < 48 * w + 48; ++h) {
    float kv = Wk[h * EE + kcol];
    const float* qp = Wq + h * EE + e1b;
    float4 q0 = *(const float4*)qp, q1 = *(const float4*)(qp + 4);
    acc[0] += q0.x * kv; acc[1] += q0.y * kv;
    acc[2] += q0.z * kv; acc[3] += q0.w * kv;
    acc[4] += q1.x * kv; acc[5] += q1.y * kv;
    acc[6] += q1.z * kv; acc[7] += q1.w * kv;
  }
#pragma unroll
  for (int j = 0; j < 8; ++j) red[w][lane][j] = acc[j];
  __syncthreads();
  if (w == 0) {
    union { unsigned d[4]; short8 s; } h;
#pragma unroll
    for (int i = 0; i < 4; ++i) {
      float a = red[0][lane][2*i]   + red[1][lane][2*i]   + red[2][lane][2*i]   + red[3][lane][2*i];
      float b = red[0][lane][2*i+1] + red[1][lane][2*i+1] + red[2][lane][2*i+1] + red[3][lane][2*i+1];
      h.d[i] = pack2bf(a, b);
    }
    *(short8*)((char*)out + (size_t)f * 1024 + lane * 16) = h.s;
  }
}

// ---------------------------------------------------------------------------
// proj_v: row-major GEMM for V n-tile nt; direct V^T A-frag stores (8B contig).
// Loops 4 local m-tiles; global m-tile = mtoff + mt.
// ---------------------------------------------------------------------------
__device__ __forceinline__ void proj_v(const char* smem, const short* wfv,
                                       int nt, char* vgb, int mtoff,
                                       int lg, int lr) {
  const f32x4 zero = {0.f, 0.f, 0.f, 0.f};
  const int lane = lg * 16 + lr;
  short8 wg[6];
#pragma unroll
  for (int i = 0; i < 6; ++i)
    wg[i] = *(const short8*)((const char*)wfv + ((size_t)(nt * 6 + i) * 64 + lane) * 16);
#pragma unroll
  for (int mt = 0; mt < 4; ++mt) {
    f32x4 a0 = zero;
#pragma unroll
    for (int es = 0; es < 6; ++es) {
      short8 xf = *(const short8*)(smem + (mt * 6 + es) * 1024 + lane * 16);
      a0 = __builtin_amdgcn_mfma_f32_16x16x32_bf16(xf, wg[es], a0, 0, 0, 0);
    }
    int mtg = mtoff + mt;
    union { unsigned d[2]; short4v v; } pu;
    pu.d[0] = pack2bf(a0[0], a0[1]);
    pu.d[1] = pack2bf(a0[2], a0[3]);
    *(short4v*)(vgb + (size_t)((mtg >> 1) * 12 + nt) * 1024 +
                ((2 * (mtg & 1) + (lg >> 1)) * 16 + lr) * 16 + (lg & 1) * 8) = pu.v;
  }
}

// ---------------------------------------------------------------------------
// K1 (r17-verified, ~75us): V projection + bf16 x-frag write-out.
// Block = (batch, half): 64 x-rows, 24KB LDS, 8 waves, ONE barrier.
// Staging GLOBAL-COALESCED (c4-fast). Wave w: V nt=w, plus w<4: nt=8+w.
// d_out layout per batch: xf frags [0,49152), V frags [49152,98304).
// ---------------------------------------------------------------------------
__global__ __launch_bounds__(512)
void v_gemm(const float* __restrict__ x, const short* __restrict__ wfv,
            char* __restrict__ kvws) {
  __shared__ char smem[24576];
  const int bh = blockIdx.x, b = bh >> 1, half = bh & 1;
  const int tid = threadIdx.x;
  const int w = tid >> 6, lane = tid & 63, lg = lane >> 4, lr = lane & 15;
  const float4* xb4 = (const float4*)(x + (size_t)b * (TT * EE) + (size_t)half * 64 * EE);
  char* kvb = kvws + (size_t)b * 98304;

  // stage 64 rows -> 24 LDS frags; c4-fast (lanes read contiguous 1KB).
#pragma unroll
  for (int i = 0; i < 6; ++i) {
    int fi = tid + 512 * i;           // 3072 float4 = 64 rows x 48
    int t = fi / 48, c4 = fi % 48;
    float4 f = xb4[fi];
    union { unsigned d[2]; short4v s; } h4;
    h4.d[0] = pack2bf(f.x, f.y);
    h4.d[1] = pack2bf(f.z, f.w);
    int loff = ((t >> 4) * 6 + (c4 >> 3)) * 1024 +
               ((((c4 & 7) >> 1) << 4) + (t & 15)) * 16 + ((c4 & 1) << 3);
    *(short4v*)(smem + loff) = h4.s;
  }
  __syncthreads();

  // ---- xf write-out: linear LDS re-read -> linear global (both coalesced) ----
#pragma unroll
  for (int i = 0; i < 3; ++i) {
    int off = (w * 3 + i) * 1024 + lane * 16;
    short8 v = *(const short8*)(smem + off);
    *(short8*)(kvb + (size_t)half * 24576 + off) = v;
  }

  // ---- V projection: wave w does nt=w; waves 0-3 also nt=8+w ----
  const int mtoff = half * 4;
  char* vgb = kvb + 49152;
  proj_v(smem, wfv, w, vgb, mtoff, lg, lr);
  if (w < 4) proj_v(smem, wfv, 8 + w, vgb, mtoff, lg, lr);
}

// ---------------------------------------------------------------------------
// K2: attention with LOCAL y via LDS-staged MT (two 36KB halves), register-
// dieted: NO V prefetch (proven neutral r15/r16) — V staged global->LDS
// after S6. Block = 1 batch, 8 waves, wave = q-tile. 7 barriers.
// Phases: [MT half0 -> y ht0-5] [MT half1 -> y ht6-11] qb-shuffle [xfr->LDS]
// QK/softmax [V->LDS] PV. O overwrites kv[b] after the last barrier.
// ---------------------------------------------------------------------------
__global__ __launch_bounds__(512)
void attn_y(const short* __restrict__ wfy, char* __restrict__ kv) {
  __shared__ char smem[49152];
  const int b = blockIdx.x;
  const int tid = threadIdx.x;
  const int qt = tid >> 6, lane = tid & 63, lg = lane >> 4, lr = lane & 15;
  const char* xfb = kv + (size_t)b * 98304;  // x frags (bf16, from v_gemm)
  const char* vb  = xfb + 49152;             // V frags
  const char* wyc = (const char*)wfy;
  const f32x4 zero = {0.f, 0.f, 0.f, 0.f};

  // ---- own-tile x-frags from global (linear, coalesced) ----
  short8 xfr[6];
#pragma unroll
  for (int i = 0; i < 6; ++i)
    xfr[i] = *(const short8*)(xfb + (qt * 6 + i) * 1024 + lane * 16);

  // ---- y-phase: two MT halves staged through LDS ----
  unsigned wqp[12][2];
#pragma unroll
  for (int h = 0; h < 2; ++h) {
    if (h == 1) __syncthreads();  // S2: half0 reads done before overwrite
    // coop stage MT half h: 36 frags = 36864 B = 2304 x 16B
#pragma unroll
    for (int i = 0; i < 5; ++i) {
      int idx = tid + 512 * i;
      if (idx < 2304)
        *(short8*)(smem + idx * 16) =
            *(const short8*)(wyc + (size_t)h * 36864 + (size_t)idx * 16);
    }
    __syncthreads();  // S1/S3: MT half visible
#pragma unroll
    for (int ht2 = 0; ht2 < 6; ++ht2) {
      f32x4 a = zero;
#pragma unroll
      for (int es = 0; es < 6; ++es) {
        short8 wg = *(const short8*)(smem + (ht2 * 6 + es) * 1024 + lane * 16);
        a = __builtin_amdgcn_mfma_f32_16x16x32_bf16(wg, xfr[es], a, 0, 0, 0);
      }
      wqp[6 * h + ht2][0] = pack2bf(a[0], a[1]);
      wqp[6 * h + ht2][1] = pack2bf(a[2], a[3]);
    }
  }

  // ---- qb shuffle: lane j -> y[16qt+lr][32ha+8lg+j] ----
  short8 qb[6];
#pragma unroll
  for (int ha = 0; ha < 6; ++ha) {
    union { unsigned d[4]; short8 v; } au;
#pragma unroll
    for (int i = 0; i < 4; ++i) {
      int sl = ((2 * (lg & 1) + (i >> 1)) << 4) | lr;
      unsigned v0 = (unsigned)__shfl((int)wqp[2 * ha][i & 1], sl);
      unsigned v1 = (unsigned)__shfl((int)wqp[2 * ha + 1][i & 1], sl);
      au.d[i] = (lg >> 1) ? v1 : v0;
    }
    qb[ha] = au.v;
  }

  __syncthreads();  // S4: all waves' MT half1 reads done
  // ---- write xfr -> LDS x-frag region ----
#pragma unroll
  for (int i = 0; i < 6; ++i)
    *(short8*)(smem + (qt * 6 + i) * 1024 + lane * 16) = xfr[i];
  __syncthreads();  // S5 (=B1): x-frags visible

  // ---- S^T = mfma(x-frag, qb): lane holds S^T[16kt+4lg+r][16qt+lr] ----
  short8 pa[4];
  {
    f32x4 sa[8];
#pragma unroll
    for (int kt = 0; kt < 8; ++kt) sa[kt] = zero;
#pragma unroll
    for (int kt = 0; kt < 8; ++kt) {
      if (kt <= qt) {
#pragma unroll
        for (int ha = 0; ha < 6; ++ha) {
          short8 ka = *(const short8*)(smem + (kt * 6 + ha) * 1024 + lane * 16);
          sa[kt] = __builtin_amdgcn_mfma_f32_16x16x32_bf16(ka, qb[ha], sa[kt], 0, 0, 0);
        }
      }
    }

    // softmax over row q=16qt+lr (in-lane + 2 shfl_xor across lg)
    const float CSC = SCALE_F * LOG2E_F;
    float m = -INFINITY;
#pragma unroll
    for (int kt = 0; kt < 8; ++kt)
      if (kt <= qt) {
#pragma unroll
        for (int r = 0; r < 4; ++r) {
          float v = sa[kt][r] * CSC;
          if (kt == qt && 4 * lg + r > lr) v = -INFINITY;  // causal diagonal
          sa[kt][r] = v;
          m = fmaxf(m, v);
        }
      }
    m = fmaxf(m, __shfl_xor(m, 16));
    m = fmaxf(m, __shfl_xor(m, 32));
    float sum = 0.f;
#pragma unroll
    for (int kt = 0; kt < 8; ++kt)
      if (kt <= qt) {
#pragma unroll
        for (int r = 0; r < 4; ++r) {
          float p = exp2f(sa[kt][r] - m);
          sa[kt][r] = p;
          sum += p;
        }
      }
    sum += __shfl_xor(sum, 16);
    sum += __shfl_xor(sum, 32);
    const float rinv = 1.0f / sum;

    unsigned pw[8][2];
#pragma unroll
    for (int kt = 0; kt < 8; ++kt) { pw[kt][0] = 0u; pw[kt][1] = 0u; }
#pragma unroll
    for (int kt = 0; kt < 8; ++kt)
      if (kt <= qt) {
        pw[kt][0] = pack2bf(sa[kt][0] * rinv, sa[kt][1] * rinv);
        pw[kt][1] = pack2bf(sa[kt][2] * rinv, sa[kt][3] * rinv);
      }

    // pa[tp]: lane j -> P[q=16qt+lr][t=32tp+8lg+j]
#pragma unroll
    for (int tp = 0; tp < 4; ++tp) {
      union { unsigned d[4]; short8 v; } au;
#pragma unroll
      for (int i = 0; i < 4; ++i) {
        int sl = ((2 * (lg & 1) + (i >> 1)) << 4) | lr;
        unsigned lo = (unsigned)__shfl((int)pw[2 * tp][i & 1], sl);
        unsigned hi = (unsigned)__shfl((int)pw[2 * tp + 1][i & 1], sl);
        au.d[i] = (lg >> 1) ? hi : lo;
      }
      pa[tp] = au.v;
    }
  }
  __syncthreads();  // S6 (=B2): all x-frag LDS reads done

  // ---- stage V -> LDS (direct linear copy; no register prefetch) ----
#pragma unroll
  for (int i = 0; i < 6; ++i) {
    int off = (qt * 6 + i) * 1024 + lane * 16;
    *(short8*)(smem + off) = *(const short8*)(vb + off);
  }
  __syncthreads();  // S7 (=B3): V in LDS; all global reads of kv[b] drained

  // ---- O^T = mfma(V^T-frag, pa) in two ht-halves (peak acc 24 regs) ----
  float* ob = (float*)(kv + (size_t)b * 98304);
#pragma unroll
  for (int half = 0; half < 2; ++half) {
    f32x4 o6[6];
#pragma unroll
    for (int n = 0; n < 6; ++n) o6[n] = zero;
#pragma unroll
    for (int tp = 0; tp < 4; ++tp) {
      if (tp <= (qt >> 1)) {
#pragma unroll
        for (int n = 0; n < 6; ++n) {
          int ht = half * 6 + n;
          short8 va = *(const short8*)(smem + (tp * 12 + ht) * 1024 + lane * 16);
          o6[n] = __builtin_amdgcn_mfma_f32_16x16x32_bf16(va, pa[tp], o6[n], 0, 0, 0);
        }
      }
    }
    // lane r -> O^T[16ht+4lg+r][16qt+lr] => O[16qt+lr][16ht+4lg+r]
#pragma unroll
    for (int n = 0; n < 6; ++n)
      *(f32x4*)(ob + (16 * qt + lr) * HH + 16 * (half * 6 + n) + 4 * lg) = o6[n];
  }
}

extern "C" void kernel_launch(void* const* d_in, const int* in_sizes, int n_in,
                              void* d_out, int out_size, void* d_ws, size_t ws_size,
                              hipStream_t stream) {
  const float* x  = (const float*)d_in[0];
  const float* Wq = (const float*)d_in[1];
  const float* Wk = (const float*)d_in[2];
  const float* Wv = (const float*)d_in[3];
  int Bn = in_sizes[0] / (TT * EE);

  short* wfy = (short*)d_ws;      // MT frags, 73728 B
  short* wfv = wfy + 36864;       // Wv frags, 73728 B

  hipLaunchKernelGGL(pack_wv, dim3(18), dim3(256), 0, stream, Wv, wfv);
  hipLaunchKernelGGL(make_mt, dim3(72), dim3(256), 0, stream, Wq, Wk, wfy);
  hipLaunchKernelGGL(v_gemm, dim3(2 * Bn), dim3(512), 0, stream,
                     x, wfv, (char*)d_out);
  hipLaunchKernelGGL(attn_y, dim3(Bn), dim3(512), 0, stream,
                     wfy, (char*)d_out);
}

// Round 23
// 194.172 us; speedup vs baseline: 1.0761x; 1.0761x over previous
//
#include <hip/hip_runtime.h>
#include <hip/hip_bf16.h>

// Problem constants
#define TT 128
#define EE 192
#define HH 192
#define SCALE_F 0.07216878364870322f
#define LOG2E_F 1.4426950408889634f

typedef float f32x4 __attribute__((ext_vector_type(4)));
typedef short short8 __attribute__((ext_vector_type(8)));
typedef short short4v __attribute__((ext_vector_type(4)));

// RTNE fp32->bf16 (manual; cold kernels)
__device__ inline unsigned short f2bf(float x) {
  union { float f; unsigned u; } v; v.f = x;
  unsigned r = v.u + 0x7FFFu + ((v.u >> 16) & 1u);
  return (unsigned short)(r >> 16);
}
// hot path: packed RTNE via v_cvt_pk_bf16_f32
__device__ inline unsigned pack2bf(float a, float b) {
  __hip_bfloat162 h = __float22bfloat162_rn(float2{a, b});
  union { __hip_bfloat162 h2; unsigned u; } c; c.h2 = h;
  return c.u;
}

// ---------------------------------------------------------------------------
// pack_wv: Wv[h][e] fp32 -> frag-major bf16 (72 frags x 1KB).
// frag f = tile*6 + es; lane(lg,lr) j=0..7 -> Wv[16*tile+lr][32*es+8*lg+j]
// ---------------------------------------------------------------------------
__global__ void pack_wv(const float* __restrict__ Wv, short* __restrict__ out) {
  int f = blockIdx.x * 4 + (threadIdx.x >> 6);  // 72 frags, grid 18 x 256
  int lane = threadIdx.x & 63, lg = lane >> 4, lr = lane & 15;
  int tile = f / 6, es = f % 6;
  const float* p = Wv + (16 * tile + lr) * EE + 32 * es + 8 * lg;
  float4 a = *(const float4*)p;
  float4 b = *(const float4*)(p + 4);
  short8 h;
  h[0] = (short)f2bf(a.x); h[1] = (short)f2bf(a.y);
  h[2] = (short)f2bf(a.z); h[3] = (short)f2bf(a.w);
  h[4] = (short)f2bf(b.x); h[5] = (short)f2bf(b.y);
  h[6] = (short)f2bf(b.z); h[7] = (short)f2bf(b.w);
  *(short8*)(out + ((size_t)f * 64 + lane) * 8) = h;
}

// ---------------------------------------------------------------------------
// make_mt: MT[e2][e1] = sum_h Wq[h][e1]*Wk[h][e2], fp32 accumulate, stored
// frag-major bf16 (MT plays the "Wq" role in the transpose-proj):
// frag f = tile*6+es; lane(lg,lr) j -> MT[16*tile+lr][32*es+8*lg+j].
// ---------------------------------------------------------------------------
__global__ __launch_bounds__(256)
void make_mt(const float* __restrict__ Wq, const float* __restrict__ Wk,
             short* __restrict__ out) {
  __shared__ float red[4][64][8];
  const int f = blockIdx.x;  // 72
  const int tid = threadIdx.x;
  const int w = tid >> 6, lane = tid & 63, lg = lane >> 4, lr = lane & 15;
  const int tile = f / 6, es = f % 6;
  const int kcol = 16 * tile + lr;      // e2
  const int e1b = 32 * es + 8 * lg;     // e1 base

  float acc[8];
#pragma unroll
  for (int j = 0; j < 8; ++j) acc[j] = 0.f;
#pragma unroll 4
  for (int h = 48 * w; h < 48 * w + 48; ++h) {
    float kv = Wk[h * EE + kcol];
    const float* qp = Wq + h * EE + e1b;
    float4 q0 = *(const float4*)qp, q1 = *(const float4*)(qp + 4);
    acc[0] += q0.x * kv; acc[1] += q0.y * kv;
    acc[2] += q0.z * kv; acc[3] += q0.w * kv;
    acc[4] += q1.x * kv; acc[5] += q1.y * kv;
    acc[6] += q1.z * kv; acc[7] += q1.w * kv;
  }
#pragma unroll
  for (int j = 0; j < 8; ++j) red[w][lane][j] = acc[j];
  __syncthreads();
  if (w == 0) {
    union { unsigned d[4]; short8 s; } h;
#pragma unroll
    for (int i = 0; i < 4; ++i) {
      float a = red[0][lane][2*i]   + red[1][lane][2*i]   + red[2][lane][2*i]   + red[3][lane][2*i];
      float b = red[0][lane][2*i+1] + red[1][lane][2*i+1] + red[2][lane][2*i+1] + red[3][lane][2*i+1];
      h.d[i] = pack2bf(a, b);
    }
    *(short8*)((char*)out + (size_t)f * 1024 + lane * 16) = h.s;
  }
}

// ---------------------------------------------------------------------------
// proj_v: row-major GEMM for V n-tile nt; direct V^T A-frag stores (8B contig).
// Loops 4 local m-tiles; global m-tile = mtoff + mt.
// ---------------------------------------------------------------------------
__device__ __forceinline__ void proj_v(const char* smem, const short* wfv,
                                       int nt, char* vgb, int mtoff,
                                       int lg, int lr) {
  const f32x4 zero = {0.f, 0.f, 0.f, 0.f};
  const int lane = lg * 16 + lr;
  short8 wg[6];
#pragma unroll
  for (int i = 0; i < 6; ++i)
    wg[i] = *(const short8*)((const char*)wfv + ((size_t)(nt * 6 + i) * 64 + lane) * 16);
#pragma unroll
  for (int mt = 0; mt < 4; ++mt) {
    f32x4 a0 = zero;
#pragma unroll
    for (int es = 0; es < 6; ++es) {
      short8 xf = *(const short8*)(smem + (mt * 6 + es) * 1024 + lane * 16);
      a0 = __builtin_amdgcn_mfma_f32_16x16x32_bf16(xf, wg[es], a0, 0, 0, 0);
    }
    int mtg = mtoff + mt;
    union { unsigned d[2]; short4v v; } pu;
    pu.d[0] = pack2bf(a0[0], a0[1]);
    pu.d[1] = pack2bf(a0[2], a0[3]);
    *(short4v*)(vgb + (size_t)((mtg >> 1) * 12 + nt) * 1024 +
                ((2 * (mtg & 1) + (lg >> 1)) * 16 + lr) * 16 + (lg & 1) * 8) = pu.v;
  }
}

// ---------------------------------------------------------------------------
// K1 (r17-verified, ~75us): V projection + bf16 x-frag write-out.
// Block = (batch, half): 64 x-rows, 24KB LDS, 8 waves, ONE barrier.
// Staging GLOBAL-COALESCED (c4-fast). Wave w: V nt=w, plus w<4: nt=8+w.
// d_out layout per batch: xf frags [0,49152), V frags [49152,98304).
// ---------------------------------------------------------------------------
__global__ __launch_bounds__(512)
void v_gemm(const float* __restrict__ x, const short* __restrict__ wfv,
            char* __restrict__ kvws) {
  __shared__ char smem[24576];
  const int bh = blockIdx.x, b = bh >> 1, half = bh & 1;
  const int tid = threadIdx.x;
  const int w = tid >> 6, lane = tid & 63, lg = lane >> 4, lr = lane & 15;
  const float4* xb4 = (const float4*)(x + (size_t)b * (TT * EE) + (size_t)half * 64 * EE);
  char* kvb = kvws + (size_t)b * 98304;

  // stage 64 rows -> 24 LDS frags; c4-fast (lanes read contiguous 1KB).
#pragma unroll
  for (int i = 0; i < 6; ++i) {
    int fi = tid + 512 * i;           // 3072 float4 = 64 rows x 48
    int t = fi / 48, c4 = fi % 48;
    float4 f = xb4[fi];
    union { unsigned d[2]; short4v s; } h4;
    h4.d[0] = pack2bf(f.x, f.y);
    h4.d[1] = pack2bf(f.z, f.w);
    int loff = ((t >> 4) * 6 + (c4 >> 3)) * 1024 +
               ((((c4 & 7) >> 1) << 4) + (t & 15)) * 16 + ((c4 & 1) << 3);
    *(short4v*)(smem + loff) = h4.s;
  }
  __syncthreads();

  // ---- xf write-out: linear LDS re-read -> linear global (both coalesced) ----
#pragma unroll
  for (int i = 0; i < 3; ++i) {
    int off = (w * 3 + i) * 1024 + lane * 16;
    short8 v = *(const short8*)(smem + off);
    *(short8*)(kvb + (size_t)half * 24576 + off) = v;
  }

  // ---- V projection: wave w does nt=w; waves 0-3 also nt=8+w ----
  const int mtoff = half * 4;
  char* vgb = kvb + 49152;
  proj_v(smem, wfv, w, vgb, mtoff, lg, lr);
  if (w < 4) proj_v(smem, wfv, 8 + w, vgb, mtoff, lg, lr);
}

// ---------------------------------------------------------------------------
// K2: attention with LOCAL y, big-LDS layout (120KB, 1 block/CU is the
// residency quantum anyway): region A = x-frags [0,48K), region B = MT full
// [48K,120K) during y-phase, then V [48K,96K) for PV. ONLY 3 BARRIERS:
//   S1: x+MT staged (concurrent)  S2: MT reads done  S3: V in LDS
// V global loads issued right after S2 (T14: latency hides under QK).
// O overwrites kv[b] only after S3 (all global reads of kv[b] drained).
// ---------------------------------------------------------------------------
__global__ __launch_bounds__(512)
void attn_y(const short* __restrict__ wfy, char* __restrict__ kv) {
  extern __shared__ char smem[];       // 122880 B
  char* A = smem;                      // x-frags, 48KB
  char* B = smem + 49152;              // MT (72KB) -> V (48KB)
  const int b = blockIdx.x;
  const int tid = threadIdx.x;
  const int qt = tid >> 6, lane = tid & 63, lg = lane >> 4, lr = lane & 15;
  const char* xfb = kv + (size_t)b * 98304;  // x frags (bf16, from v_gemm)
  const char* vb  = xfb + 49152;             // V frags
  const char* wyc = (const char*)wfy;
  const f32x4 zero = {0.f, 0.f, 0.f, 0.f};

  // ---- stage x-frags -> A (6 x 16B/thread) and MT -> B (9 x 16B/thread) ----
#pragma unroll
  for (int i = 0; i < 6; ++i) {
    int off = (tid + 512 * i) * 16;    // 3072 x 16B = 48KB
    *(short8*)(A + off) = *(const short8*)(xfb + off);
  }
#pragma unroll
  for (int i = 0; i < 9; ++i) {
    int off = (tid + 512 * i) * 16;    // 4608 x 16B = 72KB
    *(short8*)(B + off) = *(const short8*)(wyc + off);
  }
  __syncthreads();  // S1: A and B populated

  // ---- own-tile x-frags from LDS (linear, conflict-free) ----
  short8 xfr[6];
#pragma unroll
  for (int i = 0; i < 6; ++i)
    xfr[i] = *(const short8*)(A + (qt * 6 + i) * 1024 + lane * 16);

  // ---- y-phase: y^T = mfma(MT-frag, xfr), MT from LDS, single pass ----
  unsigned wqp[12][2];
#pragma unroll
  for (int ht = 0; ht < 12; ++ht) {
    f32x4 a = zero;
#pragma unroll
    for (int es = 0; es < 6; ++es) {
      short8 wg = *(const short8*)(B + (ht * 6 + es) * 1024 + lane * 16);
      a = __builtin_amdgcn_mfma_f32_16x16x32_bf16(wg, xfr[es], a, 0, 0, 0);
    }
    wqp[ht][0] = pack2bf(a[0], a[1]);
    wqp[ht][1] = pack2bf(a[2], a[3]);
  }

  // ---- qb shuffle: lane j -> y[16qt+lr][32ha+8lg+j] ----
  short8 qb[6];
#pragma unroll
  for (int ha = 0; ha < 6; ++ha) {
    union { unsigned d[4]; short8 v; } au;
#pragma unroll
    for (int i = 0; i < 4; ++i) {
      int sl = ((2 * (lg & 1) + (i >> 1)) << 4) | lr;
      unsigned v0 = (unsigned)__shfl((int)wqp[2 * ha][i & 1], sl);
      unsigned v1 = (unsigned)__shfl((int)wqp[2 * ha + 1][i & 1], sl);
      au.d[i] = (lg >> 1) ? v1 : v0;
    }
    qb[ha] = au.v;
  }
  __syncthreads();  // S2: all MT reads done; B reusable for V

  // ---- V prefetch into regs (T14): issue now, ds_write after QK/softmax ----
  short8 vreg[6];
#pragma unroll
  for (int i = 0; i < 6; ++i)
    vreg[i] = *(const short8*)(vb + (qt * 6 + i) * 1024 + lane * 16);

  // ---- S^T = mfma(x-frag, qb): lane holds S^T[16kt+4lg+r][16qt+lr] ----
  short8 pa[4];
  {
    f32x4 sa[8];
#pragma unroll
    for (int kt = 0; kt < 8; ++kt) sa[kt] = zero;
#pragma unroll
    for (int kt = 0; kt < 8; ++kt) {
      if (kt <= qt) {
#pragma unroll
        for (int ha = 0; ha < 6; ++ha) {
          short8 ka = *(const short8*)(A + (kt * 6 + ha) * 1024 + lane * 16);
          sa[kt] = __builtin_amdgcn_mfma_f32_16x16x32_bf16(ka, qb[ha], sa[kt], 0, 0, 0);
        }
      }
    }

    // softmax over row q=16qt+lr (in-lane + 2 shfl_xor across lg)
    const float CSC = SCALE_F * LOG2E_F;
    float m = -INFINITY;
#pragma unroll
    for (int kt = 0; kt < 8; ++kt)
      if (kt <= qt) {
#pragma unroll
        for (int r = 0; r < 4; ++r) {
          float v = sa[kt][r] * CSC;
          if (kt == qt && 4 * lg + r > lr) v = -INFINITY;  // causal diagonal
          sa[kt][r] = v;
          m = fmaxf(m, v);
        }
      }
    m = fmaxf(m, __shfl_xor(m, 16));
    m = fmaxf(m, __shfl_xor(m, 32));
    float sum = 0.f;
#pragma unroll
    for (int kt = 0; kt < 8; ++kt)
      if (kt <= qt) {
#pragma unroll
        for (int r = 0; r < 4; ++r) {
          float p = exp2f(sa[kt][r] - m);
          sa[kt][r] = p;
          sum += p;
        }
      }
    sum += __shfl_xor(sum, 16);
    sum += __shfl_xor(sum, 32);
    const float rinv = 1.0f / sum;

    unsigned pw[8][2];
#pragma unroll
    for (int kt = 0; kt < 8; ++kt) { pw[kt][0] = 0u; pw[kt][1] = 0u; }
#pragma unroll
    for (int kt = 0; kt < 8; ++kt)
      if (kt <= qt) {
        pw[kt][0] = pack2bf(sa[kt][0] * rinv, sa[kt][1] * rinv);
        pw[kt][1] = pack2bf(sa[kt][2] * rinv, sa[kt][3] * rinv);
      }

    // pa[tp]: lane j -> P[q=16qt+lr][t=32tp+8lg+j]
#pragma unroll
    for (int tp = 0; tp < 4; ++tp) {
      union { unsigned d[4]; short8 v; } au;
#pragma unroll
      for (int i = 0; i < 4; ++i) {
        int sl = ((2 * (lg & 1) + (i >> 1)) << 4) | lr;
        unsigned lo = (unsigned)__shfl((int)pw[2 * tp][i & 1], sl);
        unsigned hi = (unsigned)__shfl((int)pw[2 * tp + 1][i & 1], sl);
        au.d[i] = (lg >> 1) ? hi : lo;
      }
      pa[tp] = au.v;
    }
  }

  // ---- write prefetched V -> B ----
#pragma unroll
  for (int i = 0; i < 6; ++i)
    *(short8*)(B + (qt * 6 + i) * 1024 + lane * 16) = vreg[i];
  __syncthreads();  // S3: V in LDS; all global reads of kv[b] drained

  // ---- O^T = mfma(V^T-frag, pa) in two ht-halves (peak acc 24 regs) ----
  float* ob = (float*)(kv + (size_t)b * 98304);
#pragma unroll
  for (int half = 0; half < 2; ++half) {
    f32x4 o6[6];
#pragma unroll
    for (int n = 0; n < 6; ++n) o6[n] = zero;
#pragma unroll
    for (int tp = 0; tp < 4; ++tp) {
      if (tp <= (qt >> 1)) {
#pragma unroll
        for (int n = 0; n < 6; ++n) {
          int ht = half * 6 + n;
          short8 va = *(const short8*)(B + (tp * 12 + ht) * 1024 + lane * 16);
          o6[n] = __builtin_amdgcn_mfma_f32_16x16x32_bf16(va, pa[tp], o6[n], 0, 0, 0);
        }
      }
    }
    // lane r -> O^T[16ht+4lg+r][16qt+lr] => O[16qt+lr][16ht+4lg+r]
#pragma unroll
    for (int n = 0; n < 6; ++n)
      *(f32x4*)(ob + (16 * qt + lr) * HH + 16 * (half * 6 + n) + 4 * lg) = o6[n];
  }
}

extern "C" void kernel_launch(void* const* d_in, const int* in_sizes, int n_in,
                              void* d_out, int out_size, void* d_ws, size_t ws_size,
                              hipStream_t stream) {
  const float* x  = (const float*)d_in[0];
  const float* Wq = (const float*)d_in[1];
  const float* Wk = (const float*)d_in[2];
  const float* Wv = (const float*)d_in[3];
  int Bn = in_sizes[0] / (TT * EE);

  short* wfy = (short*)d_ws;      // MT frags, 73728 B
  short* wfv = wfy + 36864;       // Wv frags, 73728 B

  hipLaunchKernelGGL(pack_wv, dim3(18), dim3(256), 0, stream, Wv, wfv);
  hipLaunchKernelGGL(make_mt, dim3(72), dim3(256), 0, stream, Wq, Wk, wfy);
  hipLaunchKernelGGL(v_gemm, dim3(2 * Bn), dim3(512), 0, stream,
                     x, wfv, (char*)d_out);
  hipLaunchKernelGGL(attn_y, dim3(Bn), dim3(512), 122880, stream,
                     wfy, (char*)d_out);
}

// Round 24
// 170.898 us; speedup vs baseline: 1.2227x; 1.1362x over previous
//
#include <hip/hip_runtime.h>
#include <hip/hip_bf16.h>

// Problem constants
#define TT 128
#define EE 192
#define HH 192
#define SCALE_F 0.07216878364870322f
#define LOG2E_F 1.4426950408889634f

typedef float f32x4 __attribute__((ext_vector_type(4)));
typedef short short8 __attribute__((ext_vector_type(8)));
typedef short short4v __attribute__((ext_vector_type(4)));

// RTNE fp32->bf16 (manual; cold kernels)
__device__ inline unsigned short f2bf(float x) {
  union { float f; unsigned u; } v; v.f = x;
  unsigned r = v.u + 0x7FFFu + ((v.u >> 16) & 1u);
  return (unsigned short)(r >> 16);
}
// hot path: packed RTNE via v_cvt_pk_bf16_f32
__device__ inline unsigned pack2bf(float a, float b) {
  __hip_bfloat162 h = __float22bfloat162_rn(float2{a, b});
  union { __hip_bfloat162 h2; unsigned u; } c; c.h2 = h;
  return c.u;
}

// ---------------------------------------------------------------------------
// pack_wv: Wv[h][e] fp32 -> frag-major bf16 (72 frags x 1KB).
// frag f = tile*6 + es; lane(lg,lr) j=0..7 -> Wv[16*tile+lr][32*es+8*lg+j]
// ---------------------------------------------------------------------------
__global__ void pack_wv(const float* __restrict__ Wv, short* __restrict__ out) {
  int f = blockIdx.x * 4 + (threadIdx.x >> 6);  // 72 frags, grid 18 x 256
  int lane = threadIdx.x & 63, lg = lane >> 4, lr = lane & 15;
  int tile = f / 6, es = f % 6;
  const float* p = Wv + (16 * tile + lr) * EE + 32 * es + 8 * lg;
  float4 a = *(const float4*)p;
  float4 b = *(const float4*)(p + 4);
  short8 h;
  h[0] = (short)f2bf(a.x); h[1] = (short)f2bf(a.y);
  h[2] = (short)f2bf(a.z); h[3] = (short)f2bf(a.w);
  h[4] = (short)f2bf(b.x); h[5] = (short)f2bf(b.y);
  h[6] = (short)f2bf(b.z); h[7] = (short)f2bf(b.w);
  *(short8*)(out + ((size_t)f * 64 + lane) * 8) = h;
}

// ---------------------------------------------------------------------------
// make_mt: MT[e2][e1] = sum_h Wq[h][e1]*Wk[h][e2], fp32 accumulate, stored
// frag-major bf16 (MT plays the "Wq" role in the transpose-proj):
// frag f = tile*6+es; lane(lg,lr) j -> MT[16*tile+lr][32*es+8*lg+j].
// ---------------------------------------------------------------------------
__global__ __launch_bounds__(256)
void make_mt(const float* __restrict__ Wq, const float* __restrict__ Wk,
             short* __restrict__ out) {
  __shared__ float red[4][64][8];
  const int f = blockIdx.x;  // 72
  const int tid = threadIdx.x;
  const int w = tid >> 6, lane = tid & 63, lg = lane >> 4, lr = lane & 15;
  const int tile = f / 6, es = f % 6;
  const int kcol = 16 * tile + lr;      // e2
  const int e1b = 32 * es + 8 * lg;     // e1 base

  float acc[8];
#pragma unroll
  for (int j = 0; j < 8; ++j) acc[j] = 0.f;
#pragma unroll 4
  for (int h = 48 * w; h < 48 * w + 48; ++h) {
    float kv = Wk[h * EE + kcol];
    const float* qp = Wq + h * EE + e1b;
    float4 q0 = *(const float4*)qp, q1 = *(const float4*)(qp + 4);
    acc[0] += q0.x * kv; acc[1] += q0.y * kv;
    acc[2] += q0.z * kv; acc[3] += q0.w * kv;
    acc[4] += q1.x * kv; acc[5] += q1.y * kv;
    acc[6] += q1.z * kv; acc[7] += q1.w * kv;
  }
#pragma unroll
  for (int j = 0; j < 8; ++j) red[w][lane][j] = acc[j];
  __syncthreads();
  if (w == 0) {
    union { unsigned d[4]; short8 s; } h;
#pragma unroll
    for (int i = 0; i < 4; ++i) {
      float a = red[0][lane][2*i]   + red[1][lane][2*i]   + red[2][lane][2*i]   + red[3][lane][2*i];
      float b = red[0][lane][2*i+1] + red[1][lane][2*i+1] + red[2][lane][2*i+1] + red[3][lane][2*i+1];
      h.d[i] = pack2bf(a, b);
    }
    *(short8*)((char*)out + (size_t)f * 1024 + lane * 16) = h.s;
  }
}

// ---------------------------------------------------------------------------
// attn_fused: whole op per batch, ONE kernel, 132KB LDS, 3 barriers.
// LDS: A = x-frags [0,48K) ; C = V-frags [48K,96K) ; D = MT half [96K,132K).
// Phases: {x->A, MT.h0->D} S1 {V-proj A->C, y.h0(D)} S2 {MT.h1->D} S3
//         {y.h1(D), qb-shuffle, QK(A), softmax, PV(C), O->out}.
// Wave w = q-tile. V units: nt=w all waves; nt=8+w for w<4 (balances small-qt
// waves' lighter QK/PV). O goes straight to d_out (no aliasing, no races).
// ---------------------------------------------------------------------------
__global__ __launch_bounds__(512)
void attn_fused(const float* __restrict__ x, const short* __restrict__ wfy,
                const short* __restrict__ wfv, float* __restrict__ out) {
  extern __shared__ char smem[];       // 135168 B
  char* A = smem;                      // x-frags 48KB
  char* C = smem + 49152;              // V-frags 48KB
  char* D = smem + 98304;              // MT half 36KB
  const int b = blockIdx.x;
  const int tid = threadIdx.x;
  const int qt = tid >> 6, lane = tid & 63, lg = lane >> 4, lr = lane & 15;
  const float4* xb4 = (const float4*)(x + (size_t)b * (TT * EE));
  const char* wyc = (const char*)wfy;
  const f32x4 zero = {0.f, 0.f, 0.f, 0.f};

  // ---- stage x -> A (c4-fast, verified map) and MT half0 -> D ----
#pragma unroll
  for (int i = 0; i < 12; ++i) {
    int fi = tid + 512 * i;           // 6144 float4 = 128 rows x 48
    int t = fi / 48, c4 = fi % 48;
    float4 f = xb4[fi];
    union { unsigned d[2]; short4v s; } h4;
    h4.d[0] = pack2bf(f.x, f.y);
    h4.d[1] = pack2bf(f.z, f.w);
    int loff = ((t >> 4) * 6 + (c4 >> 3)) * 1024 +
               ((((c4 & 7) >> 1) << 4) + (t & 15)) * 16 + ((c4 & 1) << 3);
    *(short4v*)(A + loff) = h4.s;
  }
#pragma unroll
  for (int i = 0; i < 5; ++i) {
    int idx = tid + 512 * i;          // 2304 x 16B = 36KB
    if (idx < 2304)
      *(short8*)(D + idx * 16) = *(const short8*)(wyc + (size_t)idx * 16);
  }
  __syncthreads();  // S1: A and D(half0) populated

  // ---- V projection into C: wave qt does nt=qt; qt<4 also nt=8+qt ----
  {
    const short* wfvp = wfv;
#pragma unroll
    for (int u = 0; u < 2; ++u) {
      int nt = (u == 0) ? qt : (8 + qt);
      if (u == 1 && qt >= 4) break;
      short8 wg[6];
#pragma unroll
      for (int i = 0; i < 6; ++i)
        wg[i] = *(const short8*)((const char*)wfvp +
                 ((size_t)(nt * 6 + i) * 64 + lane) * 16);
#pragma unroll
      for (int mt = 0; mt < 8; ++mt) {
        f32x4 a0 = zero;
#pragma unroll
        for (int es = 0; es < 6; ++es) {
          short8 xf = *(const short8*)(A + (mt * 6 + es) * 1024 + lane * 16);
          a0 = __builtin_amdgcn_mfma_f32_16x16x32_bf16(xf, wg[es], a0, 0, 0, 0);
        }
        // V[16mt+4lg+r][16nt+lr] -> C frag(tp=mt>>1, ht=nt),
        //   lane(2*(mt&1)+(lg>>1), lr), 8B at sub-offset (lg&1)*8
        union { unsigned d[2]; short4v v; } pu;
        pu.d[0] = pack2bf(a0[0], a0[1]);
        pu.d[1] = pack2bf(a0[2], a0[3]);
        *(short4v*)(C + ((mt >> 1) * 12 + nt) * 1024 +
                    ((2 * (mt & 1) + (lg >> 1)) * 16 + lr) * 16 + ((lg & 1) << 3)) = pu.v;
      }
    }
  }

  // ---- own-tile x-frags (for y-phase B operand) ----
  short8 xfr[6];
#pragma unroll
  for (int i = 0; i < 6; ++i)
    xfr[i] = *(const short8*)(A + (qt * 6 + i) * 1024 + lane * 16);

  // ---- y-phase half0: ht 0..5 from D ----
  unsigned wqp[12][2];
#pragma unroll
  for (int ht = 0; ht < 6; ++ht) {
    f32x4 a = zero;
#pragma unroll
    for (int es = 0; es < 6; ++es) {
      short8 wg = *(const short8*)(D + (ht * 6 + es) * 1024 + lane * 16);
      a = __builtin_amdgcn_mfma_f32_16x16x32_bf16(wg, xfr[es], a, 0, 0, 0);
    }
    wqp[ht][0] = pack2bf(a[0], a[1]);
    wqp[ht][1] = pack2bf(a[2], a[3]);
  }
  __syncthreads();  // S2: D(half0) reads + C writes complete

  // ---- stage MT half1 -> D ----
#pragma unroll
  for (int i = 0; i < 5; ++i) {
    int idx = tid + 512 * i;
    if (idx < 2304)
      *(short8*)(D + idx * 16) =
          *(const short8*)(wyc + 36864 + (size_t)idx * 16);
  }
  __syncthreads();  // S3: D(half1) populated

  // ---- y-phase half1: ht 6..11 ----
#pragma unroll
  for (int ht = 0; ht < 6; ++ht) {
    f32x4 a = zero;
#pragma unroll
    for (int es = 0; es < 6; ++es) {
      short8 wg = *(const short8*)(D + (ht * 6 + es) * 1024 + lane * 16);
      a = __builtin_amdgcn_mfma_f32_16x16x32_bf16(wg, xfr[es], a, 0, 0, 0);
    }
    wqp[6 + ht][0] = pack2bf(a[0], a[1]);
    wqp[6 + ht][1] = pack2bf(a[2], a[3]);
  }

  // ---- qb shuffle: lane j -> y[16qt+lr][32ha+8lg+j] ----
  short8 qb[6];
#pragma unroll
  for (int ha = 0; ha < 6; ++ha) {
    union { unsigned d[4]; short8 v; } au;
#pragma unroll
    for (int i = 0; i < 4; ++i) {
      int sl = ((2 * (lg & 1) + (i >> 1)) << 4) | lr;
      unsigned v0 = (unsigned)__shfl((int)wqp[2 * ha][i & 1], sl);
      unsigned v1 = (unsigned)__shfl((int)wqp[2 * ha + 1][i & 1], sl);
      au.d[i] = (lg >> 1) ? v1 : v0;
    }
    qb[ha] = au.v;
  }

  // ---- S^T = mfma(x-frag, qb): lane holds S^T[16kt+4lg+r][16qt+lr] ----
  short8 pa[4];
  {
    f32x4 sa[8];
#pragma unroll
    for (int kt = 0; kt < 8; ++kt) sa[kt] = zero;
#pragma unroll
    for (int kt = 0; kt < 8; ++kt) {
      if (kt <= qt) {
#pragma unroll
        for (int ha = 0; ha < 6; ++ha) {
          short8 ka = *(const short8*)(A + (kt * 6 + ha) * 1024 + lane * 16);
          sa[kt] = __builtin_amdgcn_mfma_f32_16x16x32_bf16(ka, qb[ha], sa[kt], 0, 0, 0);
        }
      }
    }

    // softmax over row q=16qt+lr (in-lane + 2 shfl_xor across lg)
    const float CSC = SCALE_F * LOG2E_F;
    float m = -INFINITY;
#pragma unroll
    for (int kt = 0; kt < 8; ++kt)
      if (kt <= qt) {
#pragma unroll
        for (int r = 0; r < 4; ++r) {
          float v = sa[kt][r] * CSC;
          if (kt == qt && 4 * lg + r > lr) v = -INFINITY;  // causal diagonal
          sa[kt][r] = v;
          m = fmaxf(m, v);
        }
      }
    m = fmaxf(m, __shfl_xor(m, 16));
    m = fmaxf(m, __shfl_xor(m, 32));
    float sum = 0.f;
#pragma unroll
    for (int kt = 0; kt < 8; ++kt)
      if (kt <= qt) {
#pragma unroll
        for (int r = 0; r < 4; ++r) {
          float p = exp2f(sa[kt][r] - m);
          sa[kt][r] = p;
          sum += p;
        }
      }
    sum += __shfl_xor(sum, 16);
    sum += __shfl_xor(sum, 32);
    const float rinv = 1.0f / sum;

    unsigned pw[8][2];
#pragma unroll
    for (int kt = 0; kt < 8; ++kt) { pw[kt][0] = 0u; pw[kt][1] = 0u; }
#pragma unroll
    for (int kt = 0; kt < 8; ++kt)
      if (kt <= qt) {
        pw[kt][0] = pack2bf(sa[kt][0] * rinv, sa[kt][1] * rinv);
        pw[kt][1] = pack2bf(sa[kt][2] * rinv, sa[kt][3] * rinv);
      }

    // pa[tp]: lane j -> P[q=16qt+lr][t=32tp+8lg+j]
#pragma unroll
    for (int tp = 0; tp < 4; ++tp) {
      union { unsigned d[4]; short8 v; } au;
#pragma unroll
      for (int i = 0; i < 4; ++i) {
        int sl = ((2 * (lg & 1) + (i >> 1)) << 4) | lr;
        unsigned lo = (unsigned)__shfl((int)pw[2 * tp][i & 1], sl);
        unsigned hi = (unsigned)__shfl((int)pw[2 * tp + 1][i & 1], sl);
        au.d[i] = (lg >> 1) ? hi : lo;
      }
      pa[tp] = au.v;
    }
  }

  // ---- O^T = mfma(V^T-frag(C), pa) in two ht-halves; store to d_out ----
  float* ob = out + (size_t)b * (TT * HH);
#pragma unroll
  for (int half = 0; half < 2; ++half) {
    f32x4 o6[6];
#pragma unroll
    for (int n = 0; n < 6; ++n) o6[n] = zero;
#pragma unroll
    for (int tp = 0; tp < 4; ++tp) {
      if (tp <= (qt >> 1)) {
#pragma unroll
        for (int n = 0; n < 6; ++n) {
          int ht = half * 6 + n;
          short8 va = *(const short8*)(C + (tp * 12 + ht) * 1024 + lane * 16);
          o6[n] = __builtin_amdgcn_mfma_f32_16x16x32_bf16(va, pa[tp], o6[n], 0, 0, 0);
        }
      }
    }
    // lane r -> O^T[16ht+4lg+r][16qt+lr] => O[16qt+lr][16ht+4lg+r]
#pragma unroll
    for (int n = 0; n < 6; ++n)
      *(f32x4*)(ob + (16 * qt + lr) * HH + 16 * (half * 6 + n) + 4 * lg) = o6[n];
  }
}

extern "C" void kernel_launch(void* const* d_in, const int* in_sizes, int n_in,
                              void* d_out, int out_size, void* d_ws, size_t ws_size,
                              hipStream_t stream) {
  const float* x  = (const float*)d_in[0];
  const float* Wq = (const float*)d_in[1];
  const float* Wk = (const float*)d_in[2];
  const float* Wv = (const float*)d_in[3];
  int Bn = in_sizes[0] / (TT * EE);

  short* wfy = (short*)d_ws;      // MT frags, 73728 B
  short* wfv = wfy + 36864;       // Wv frags, 73728 B

  hipLaunchKernelGGL(pack_wv, dim3(18), dim3(256), 0, stream, Wv, wfv);
  hipLaunchKernelGGL(make_mt, dim3(72), dim3(256), 0, stream, Wq, Wk, wfy);
  hipLaunchKernelGGL(attn_fused, dim3(Bn), dim3(512), 135168, stream,
                     x, wfy, wfv, (float*)d_out);
}